// Round 1
// 260.392 us; speedup vs baseline: 1.0451x; 1.0451x over previous
//
#include <hip/hip_runtime.h>
#include <stdint.h>

#define N_SPK 512
#define N_UTT 64
#define DIM   1024
#define NROWS (N_SPK * N_UTT)   // 32768
#define EPS   1e-6f

#define BM 128
#define BN 128
#define BK 32
#define KTILES (DIM / BK)       // 32

typedef __attribute__((ext_vector_type(8))) short short8;
typedef __attribute__((ext_vector_type(4))) float f32x4;

__device__ __forceinline__ uint16_t f2bf(float f) {
    union { float f; uint32_t i; } un; un.f = f;
    uint32_t x = un.i;
    return (uint16_t)((x + 0x7fffu + ((x >> 16) & 1u)) >> 16);
}

// K1: one block per speaker. 4 waves x 16 rows each, processed 4 rows at a
// time (16 float4 loads in flight). Produces: xb (bf16 cast of x), xxg (per-row
// |x|^2), and -- since the whole speaker is in-block -- the normalized centroid
// cmat + ssqg directly. Eliminates the old Sg4 partial round-trip (16 MB) and
// the separate centroid kernel.
__global__ __launch_bounds__(256) void prep_centroid(
    const float* __restrict__ x, uint16_t* __restrict__ xb,
    uint16_t* __restrict__ cmat, float* __restrict__ xxg,
    float* __restrict__ ssqg)
{
    const int n    = blockIdx.x;
    const int tid  = threadIdx.x;
    const int lane = tid & 63;
    const int w    = tid >> 6;

    const float* xn  = x  + (size_t)n * N_UTT * DIM;
    uint16_t*    xbn = xb + (size_t)n * N_UTT * DIM;

    // per-lane running column sums over this wave's 16 rows
    float Sp[16];
    #pragma unroll
    for (int j = 0; j < 16; ++j) Sp[j] = 0.f;

    #pragma unroll 1   // keep 16 loads in flight per pass; don't hoist 64
    for (int o = 0; o < 4; ++o) {
        const int m0 = w * 16 + o * 4;

        float4 v[16];
        #pragma unroll
        for (int i = 0; i < 4; ++i)
            #pragma unroll
            for (int j = 0; j < 4; ++j)
                v[i * 4 + j] = *(const float4*)(xn + (size_t)(m0 + i) * DIM + j * 256 + lane * 4);

        float xx[4] = {0.f, 0.f, 0.f, 0.f};
        #pragma unroll
        for (int i = 0; i < 4; ++i) {
            #pragma unroll
            for (int j = 0; j < 4; ++j) {
                const float4 q = v[i * 4 + j];
                xx[i] += q.x * q.x + q.y * q.y + q.z * q.z + q.w * q.w;
                Sp[j * 4 + 0] += q.x; Sp[j * 4 + 1] += q.y;
                Sp[j * 4 + 2] += q.z; Sp[j * 4 + 3] += q.w;
                ushort4 ov;
                ov.x = f2bf(q.x); ov.y = f2bf(q.y); ov.z = f2bf(q.z); ov.w = f2bf(q.w);
                *(ushort4*)(xbn + (size_t)(m0 + i) * DIM + j * 256 + lane * 4) = ov;
            }
        }

        #pragma unroll
        for (int i = 0; i < 4; ++i) {
            float t = xx[i];
            #pragma unroll
            for (int off = 1; off < 64; off <<= 1) t += __shfl_xor(t, off);
            if (lane == 0) xxg[n * N_UTT + m0 + i] = t;
        }
    }

    // cross-wave combine of column sums -> full speaker sum S
    __shared__ float Sh[4][DIM];   // 16 KB
    #pragma unroll
    for (int j = 0; j < 4; ++j)
        *(float4*)&Sh[w][j * 256 + lane * 4] =
            make_float4(Sp[j * 4], Sp[j * 4 + 1], Sp[j * 4 + 2], Sp[j * 4 + 3]);
    __syncthreads();

    const int d0 = tid * 4;
    float4 S  = *(const float4*)&Sh[0][d0];
    const float4 b1 = *(const float4*)&Sh[1][d0];
    const float4 b2 = *(const float4*)&Sh[2][d0];
    const float4 b3 = *(const float4*)&Sh[3][d0];
    S.x += b1.x + b2.x + b3.x; S.y += b1.y + b2.y + b3.y;
    S.z += b1.z + b2.z + b3.z; S.w += b1.w + b2.w + b3.w;

    // |S|^2 across the block
    float css = S.x * S.x + S.y * S.y + S.z * S.z + S.w * S.w;
    #pragma unroll
    for (int off = 1; off < 64; off <<= 1) css += __shfl_xor(css, off);
    __shared__ float red[4];
    if ((tid & 63) == 0) red[tid >> 6] = css;
    __syncthreads();
    const float ssq = red[0] + red[1] + red[2] + red[3];

    // centroid = S/64; l2norm scale = rsqrt(max(|S/64|^2, EPS)) / 64
    const float scale = rsqrtf(fmaxf(ssq * (1.0f / 4096.f), EPS)) * (1.0f / 64.f);
    ushort4 oc;
    oc.x = f2bf(S.x * scale); oc.y = f2bf(S.y * scale);
    oc.z = f2bf(S.z * scale); oc.w = f2bf(S.w * scale);
    *(ushort4*)(cmat + (size_t)n * DIM + d0) = oc;
    if (tid == 0) ssqg[n] = ssq;
}

// K2: bf16 MFMA GEMM (A = xb [32768 x 1024], B^T = cmat [512 x 1024]).
// Epilogue: off-diag sim = w*dot*rn + b; diag reconstructs cos_self from
// (dot*|S|, xx, ssq), stores pos[R]. Row partial sums of exp combined across
// the two waveN halves via LDS, plain-stored to sumexp4[ct]. (unchanged)
__global__ __launch_bounds__(256) void gemm_lse_kernel(
    const uint16_t* __restrict__ xb, const uint16_t* __restrict__ cmat,
    const float* __restrict__ xxg, const float* __restrict__ ssqg,
    const float* __restrict__ wp, const float* __restrict__ bp,
    float* __restrict__ sumexp4, float* __restrict__ pos)
{
    __shared__ uint16_t Asm[BM * BK];   // 8 KB
    __shared__ uint16_t Bsm[BN * BK];   // 8 KB
    __shared__ float    SeLDS[BM];      // 512 B, epilogue combine

    const int tid   = threadIdx.x;
    const int lane  = tid & 63;
    const int wid   = tid >> 6;
    const int waveM = wid >> 1;
    const int waveN = wid & 1;

    const int bid = blockIdx.x;
    const int rt  = (bid & 7) | ((bid >> 5) << 3);
    const int ct  = (bid >> 3) & 3;

    const int rowBase = rt * BM;
    const int colBase = ct * BN;

    const uint16_t* gA[2];
    const uint16_t* gB[2];
    #pragma unroll
    for (int i = 0; i < 2; ++i) {
        const int s    = i * 256 + tid;
        const int srow = s >> 2;
        const int kc   = (s & 3) ^ ((srow >> 1) & 3);
        gA[i] = xb   + (size_t)(rowBase + srow) * DIM + kc * 8;
        gB[i] = cmat + (size_t)(colBase + srow) * DIM + kc * 8;
    }

    f32x4 acc[4][4];
    #pragma unroll
    for (int i = 0; i < 4; ++i)
        #pragma unroll
        for (int j = 0; j < 4; ++j)
            acc[i][j] = (f32x4){0.f, 0.f, 0.f, 0.f};

    const int cL  = lane & 15;
    const int q   = lane >> 4;
    const int key = (cL >> 1) & 3;
    const int kcs = q ^ key;

    for (int kt = 0; kt < KTILES; ++kt) {
        __syncthreads();
        const int ko = kt * BK;
        #pragma unroll
        for (int i = 0; i < 2; ++i) {
            __builtin_amdgcn_global_load_lds(
                (const __attribute__((address_space(1))) void*)(gA[i] + ko),
                (__attribute__((address_space(3))) void*)(&Asm[(i * 256 + wid * 64) * 8]),
                16, 0, 0);
            __builtin_amdgcn_global_load_lds(
                (const __attribute__((address_space(1))) void*)(gB[i] + ko),
                (__attribute__((address_space(3))) void*)(&Bsm[(i * 256 + wid * 64) * 8]),
                16, 0, 0);
        }
        __syncthreads();

        short8 a[4], b[4];
        #pragma unroll
        for (int bi = 0; bi < 4; ++bi)
            a[bi] = *(const short8*)&Asm[(waveM * 64 + bi * 16 + cL) * BK + kcs * 8];
        #pragma unroll
        for (int bj = 0; bj < 4; ++bj)
            b[bj] = *(const short8*)&Bsm[(waveN * 64 + bj * 16 + cL) * BK + kcs * 8];

        #pragma unroll
        for (int bi = 0; bi < 4; ++bi)
            #pragma unroll
            for (int bj = 0; bj < 4; ++bj)
                acc[bi][bj] = __builtin_amdgcn_mfma_f32_16x16x32_bf16(
                    a[bi], b[bj], acc[bi][bj], 0, 0, 0);
    }

    const float wv = wp[0], bv = bp[0];
    float srow[16];
    #pragma unroll
    for (int bi = 0; bi < 4; ++bi) {
        #pragma unroll
        for (int r = 0; r < 4; ++r) {
            const int R     = rowBase + waveM * 64 + bi * 16 + q * 4 + r;
            const float xxv = xxg[R];
            const float rn  = rsqrtf(fmaxf(xxv, EPS));
            const int nrow  = R >> 6;
            float s = 0.f;
            #pragma unroll
            for (int bj = 0; bj < 4; ++bj) {
                const int col = colBase + waveN * 64 + bj * 16 + cL;
                const float dot = acc[bi][bj][r];
                float sim;
                if (col == nrow) {
                    const float ssqv = ssqg[nrow];
                    const float xs   = dot * sqrtf(ssqv);
                    const float d2   = ssqv - 2.f * xs + xxv;
                    const float cs   = ((xs - xxv) * (1.f / 63.f)) * rn *
                                       rsqrtf(fmaxf(d2 * (1.f / 3969.f), EPS));
                    sim = wv * cs + bv;
                    pos[R] = sim;
                } else {
                    sim = wv * (dot * rn) + bv;
                }
                s += __expf(sim);
            }
            #pragma unroll
            for (int off = 1; off < 16; off <<= 1) s += __shfl_xor(s, off);
            srow[bi * 4 + r] = s;
        }
    }

    if (waveN == 1 && cL == 0) {
        #pragma unroll
        for (int bi = 0; bi < 4; ++bi)
            #pragma unroll
            for (int r = 0; r < 4; ++r)
                SeLDS[waveM * 64 + bi * 16 + q * 4 + r] = srow[bi * 4 + r];
    }
    __syncthreads();
    if (waveN == 0 && cL == 0) {
        #pragma unroll
        for (int bi = 0; bi < 4; ++bi)
            #pragma unroll
            for (int r = 0; r < 4; ++r) {
                const int lr = waveM * 64 + bi * 16 + q * 4 + r;
                sumexp4[(size_t)ct * NROWS + rowBase + lr] = srow[bi * 4 + r] + SeLDS[lr];
            }
    }
}

// K3a: 128 blocks x 256 threads; each thread owns exactly one row.
// Deterministic per-block tree reduce -> partial[b].
__global__ __launch_bounds__(256) void finalize_part(
    const float* __restrict__ pos, const float* __restrict__ se4,
    float* __restrict__ partial)
{
    const int tid = threadIdx.x;
    const int r   = blockIdx.x * 256 + tid;
    const float s = se4[r] + se4[NROWS + r] + se4[2 * NROWS + r] + se4[3 * NROWS + r];
    float acc = __logf(s) - pos[r];
    #pragma unroll
    for (int off = 1; off < 64; off <<= 1) acc += __shfl_xor(acc, off);
    __shared__ float red[4];
    if ((tid & 63) == 0) red[tid >> 6] = acc;
    __syncthreads();
    if (tid == 0) partial[blockIdx.x] = red[0] + red[1] + red[2] + red[3];
}

// K3b: single tiny block sums the 128 partials.
__global__ __launch_bounds__(128) void finalize_sum(
    const float* __restrict__ partial, float* __restrict__ out)
{
    const int tid = threadIdx.x;
    float t = partial[tid];
    #pragma unroll
    for (int off = 1; off < 64; off <<= 1) t += __shfl_xor(t, off);
    __shared__ float red[2];
    if ((tid & 63) == 0) red[tid >> 6] = t;
    __syncthreads();
    if (tid == 0) out[0] = red[0] + red[1];
}

extern "C" void kernel_launch(void* const* d_in, const int* in_sizes, int n_in,
                              void* d_out, int out_size, void* d_ws, size_t ws_size,
                              hipStream_t stream)
{
    const float* x  = (const float*)d_in[0];
    const float* wp = (const float*)d_in[1];
    const float* bp = (const float*)d_in[2];
    float* out = (float*)d_out;

    char* ws = (char*)d_ws;
    size_t off = 0;
    uint16_t* xb      = (uint16_t*)(ws + off); off += (size_t)NROWS * DIM * 2;   // 64 MB
    uint16_t* cmat    = (uint16_t*)(ws + off); off += (size_t)N_SPK * DIM * 2;   // 1 MB
    float*    xxg     = (float*)(ws + off);    off += (size_t)NROWS * 4;
    float*    pos     = (float*)(ws + off);    off += (size_t)NROWS * 4;
    float*    sumexp4 = (float*)(ws + off);    off += (size_t)4 * NROWS * 4;
    float*    ssqg    = (float*)(ws + off);    off += (size_t)N_SPK * 4;
    float*    partial = (float*)(ws + off);    off += (size_t)128 * 4;

    prep_centroid<<<N_SPK, 256, 0, stream>>>(x, xb, cmat, xxg, ssqg);
    gemm_lse_kernel<<<(NROWS / BM) * (N_SPK / BN), 256, 0, stream>>>(
        xb, cmat, xxg, ssqg, wp, bp, sumexp4, pos);
    finalize_part<<<NROWS / 256, 256, 0, stream>>>(pos, sumexp4, partial);
    finalize_sum<<<1, 128, 0, stream>>>(partial, out);
}

// Round 2
// 253.451 us; speedup vs baseline: 1.0738x; 1.0274x over previous
//
#include <hip/hip_runtime.h>
#include <stdint.h>

#define N_SPK 512
#define N_UTT 64
#define DIM   1024
#define NROWS (N_SPK * N_UTT)   // 32768
#define EPS   1e-6f

// 256x256 tile, BK=32, 8 waves (2M x 4N), double-buffered LDS, 2-phase loop.
#define BM2 256
#define BN2 256
#define BK2 32
#define KT2 (DIM / BK2)         // 32

typedef __attribute__((ext_vector_type(8))) short short8;
typedef __attribute__((ext_vector_type(4))) float f32x4;

__device__ __forceinline__ uint16_t f2bf(float f) {
    union { float f; uint32_t i; } un; un.f = f;
    uint32_t x = un.i;
    return (uint16_t)((x + 0x7fffu + ((x >> 16) & 1u)) >> 16);
}

// K1: one block per speaker (unchanged from r1 — measured at BW floor).
__global__ __launch_bounds__(256) void prep_centroid(
    const float* __restrict__ x, uint16_t* __restrict__ xb,
    uint16_t* __restrict__ cmat, float* __restrict__ xxg,
    float* __restrict__ ssqg)
{
    const int n    = blockIdx.x;
    const int tid  = threadIdx.x;
    const int lane = tid & 63;
    const int w    = tid >> 6;

    const float* xn  = x  + (size_t)n * N_UTT * DIM;
    uint16_t*    xbn = xb + (size_t)n * N_UTT * DIM;

    float Sp[16];
    #pragma unroll
    for (int j = 0; j < 16; ++j) Sp[j] = 0.f;

    #pragma unroll 1
    for (int o = 0; o < 4; ++o) {
        const int m0 = w * 16 + o * 4;

        float4 v[16];
        #pragma unroll
        for (int i = 0; i < 4; ++i)
            #pragma unroll
            for (int j = 0; j < 4; ++j)
                v[i * 4 + j] = *(const float4*)(xn + (size_t)(m0 + i) * DIM + j * 256 + lane * 4);

        float xx[4] = {0.f, 0.f, 0.f, 0.f};
        #pragma unroll
        for (int i = 0; i < 4; ++i) {
            #pragma unroll
            for (int j = 0; j < 4; ++j) {
                const float4 qv = v[i * 4 + j];
                xx[i] += qv.x * qv.x + qv.y * qv.y + qv.z * qv.z + qv.w * qv.w;
                Sp[j * 4 + 0] += qv.x; Sp[j * 4 + 1] += qv.y;
                Sp[j * 4 + 2] += qv.z; Sp[j * 4 + 3] += qv.w;
                ushort4 ov;
                ov.x = f2bf(qv.x); ov.y = f2bf(qv.y); ov.z = f2bf(qv.z); ov.w = f2bf(qv.w);
                *(ushort4*)(xbn + (size_t)(m0 + i) * DIM + j * 256 + lane * 4) = ov;
            }
        }

        #pragma unroll
        for (int i = 0; i < 4; ++i) {
            float t = xx[i];
            #pragma unroll
            for (int off = 1; off < 64; off <<= 1) t += __shfl_xor(t, off);
            if (lane == 0) xxg[n * N_UTT + m0 + i] = t;
        }
    }

    __shared__ float Sh[4][DIM];
    #pragma unroll
    for (int j = 0; j < 4; ++j)
        *(float4*)&Sh[w][j * 256 + lane * 4] =
            make_float4(Sp[j * 4], Sp[j * 4 + 1], Sp[j * 4 + 2], Sp[j * 4 + 3]);
    __syncthreads();

    const int d0 = tid * 4;
    float4 S  = *(const float4*)&Sh[0][d0];
    const float4 b1 = *(const float4*)&Sh[1][d0];
    const float4 b2 = *(const float4*)&Sh[2][d0];
    const float4 b3 = *(const float4*)&Sh[3][d0];
    S.x += b1.x + b2.x + b3.x; S.y += b1.y + b2.y + b3.y;
    S.z += b1.z + b2.z + b3.z; S.w += b1.w + b2.w + b3.w;

    float css = S.x * S.x + S.y * S.y + S.z * S.z + S.w * S.w;
    #pragma unroll
    for (int off = 1; off < 64; off <<= 1) css += __shfl_xor(css, off);
    __shared__ float red[4];
    if ((tid & 63) == 0) red[tid >> 6] = css;
    __syncthreads();
    const float ssq = red[0] + red[1] + red[2] + red[3];

    const float scale = rsqrtf(fmaxf(ssq * (1.0f / 4096.f), EPS)) * (1.0f / 64.f);
    ushort4 oc;
    oc.x = f2bf(S.x * scale); oc.y = f2bf(S.y * scale);
    oc.z = f2bf(S.z * scale); oc.w = f2bf(S.w * scale);
    *(ushort4*)(cmat + (size_t)n * DIM + d0) = oc;
    if (tid == 0) ssqg[n] = ssq;
}

// K2: 256x256 bf16 MFMA GEMM, 8 waves, double-buffered LDS, 2-phase K-loop
// (STAGE next tile issued BEFORE ds_read+MFMA of current; ONE barrier/K-step;
// compiler emits the vmcnt(0)+lgkmcnt(0) drain at the barrier).
// LDS: 64 KB static total: A dbuf 2x16KB @0, B dbuf 2x16KB @32768.
// Epilogue combine buffer Se[4][256] aliases A-buf0 after the K-loop.
// XOR-chunk swizzle: stage kc=(s&3)^(srow&3); read chunk=q^(row&3) — same
// involution both sides; uniform 8-lanes-per-bank-quad on ds_read_b128.
__global__ __launch_bounds__(512, 2) void gemm_lse_kernel(
    const uint16_t* __restrict__ xb, const uint16_t* __restrict__ cmat,
    const float* __restrict__ xxg, const float* __restrict__ ssqg,
    const float* __restrict__ wp, const float* __restrict__ bp,
    float* __restrict__ sumexp2, float* __restrict__ pos)
{
    __shared__ char smem[65536];
    uint16_t* As = (uint16_t*)smem;               // [2][256*32]
    uint16_t* Bs = (uint16_t*)(smem + 32768);     // [2][256*32]
    float*    Se = (float*)smem;                  // alias of A-buf0, [4][256]

    const int tid   = threadIdx.x;
    const int lane  = tid & 63;
    const int wid   = tid >> 6;      // 0..7
    const int waveM = wid >> 2;      // 0..1 (128 rows each)
    const int waveN = wid & 3;       // 0..3 (64 cols each)

    const int bid = blockIdx.x;
    const int rt  = bid & 127;       // A-panel pair (bid, bid+128) -> same XCD
    const int ct  = bid >> 7;

    const int rowBase = rt * BM2;
    const int colBase = ct * BN2;

    // staging addresses: thread handles chunk-slots s = i*512+tid, i=0..1
    const uint16_t* gAp[2];
    const uint16_t* gBp[2];
    int ldso[2];
    #pragma unroll
    for (int i = 0; i < 2; ++i) {
        const int s    = i * 512 + tid;
        const int srow = s >> 2;                  // 0..255
        const int kc   = (s & 3) ^ (srow & 3);    // swizzled chunk fetched
        gAp[i]  = xb   + (size_t)(rowBase + srow) * DIM + kc * 8;
        gBp[i]  = cmat + (size_t)(colBase + srow) * DIM + kc * 8;
        ldso[i] = s * 16;                         // linear LDS byte offset
    }

#define STAGE(buf, ko)                                                          \
    {                                                                           \
        _Pragma("unroll")                                                       \
        for (int i_ = 0; i_ < 2; ++i_) {                                        \
            __builtin_amdgcn_global_load_lds(                                   \
                (const __attribute__((address_space(1))) void*)(gAp[i_] + (ko)),\
                (__attribute__((address_space(3))) void*)(smem + (buf) * 16384 + ldso[i_]), \
                16, 0, 0);                                                      \
            __builtin_amdgcn_global_load_lds(                                   \
                (const __attribute__((address_space(1))) void*)(gBp[i_] + (ko)),\
                (__attribute__((address_space(3))) void*)(smem + 32768 + (buf) * 16384 + ldso[i_]), \
                16, 0, 0);                                                      \
        }                                                                       \
    }

    f32x4 acc[8][4];
    #pragma unroll
    for (int i = 0; i < 8; ++i)
        #pragma unroll
        for (int j = 0; j < 4; ++j)
            acc[i][j] = (f32x4){0.f, 0.f, 0.f, 0.f};

    const int cL = lane & 15;
    const int q  = lane >> 4;

    STAGE(0, 0);                      // prologue: tile 0 into buf 0
    __syncthreads();

    int cur = 0;
    for (int kt = 0; kt < KT2; ++kt) {
        if (kt + 1 < KT2) STAGE(cur ^ 1, (kt + 1) * BK2);   // issue-early

        const uint16_t* Ab = As + cur * (256 * 32);
        const uint16_t* Bb = Bs + cur * (256 * 32);

        short8 a[8], b[4];
        #pragma unroll
        for (int bi = 0; bi < 8; ++bi) {
            const int row = waveM * 128 + bi * 16 + cL;
            const int ch  = q ^ (row & 3);
            a[bi] = *(const short8*)&Ab[row * 32 + ch * 8];
        }
        #pragma unroll
        for (int bj = 0; bj < 4; ++bj) {
            const int row = waveN * 64 + bj * 16 + cL;
            const int ch  = q ^ (row & 3);
            b[bj] = *(const short8*)&Bb[row * 32 + ch * 8];
        }

        #pragma unroll
        for (int bi = 0; bi < 8; ++bi)
            #pragma unroll
            for (int bj = 0; bj < 4; ++bj)
                acc[bi][bj] = __builtin_amdgcn_mfma_f32_16x16x32_bf16(
                    a[bi], b[bj], acc[bi][bj], 0, 0, 0);

        __syncthreads();              // one barrier per K-step
        cur ^= 1;
    }
#undef STAGE

    // epilogue: per-row exp-sum into Se[waveN][localRow], diag fixup + pos
    const float wv = wp[0], bv = bp[0];
    #pragma unroll
    for (int bi = 0; bi < 8; ++bi) {
        #pragma unroll
        for (int r = 0; r < 4; ++r) {
            const int R     = rowBase + waveM * 128 + bi * 16 + q * 4 + r;
            const float xxv = xxg[R];
            const float rn  = rsqrtf(fmaxf(xxv, EPS));
            const int nrow  = R >> 6;
            float s = 0.f;
            #pragma unroll
            for (int bj = 0; bj < 4; ++bj) {
                const int col = colBase + waveN * 64 + bj * 16 + cL;
                const float dot = acc[bi][bj][r];
                float sim;
                if (col == nrow) {
                    const float ssqv = ssqg[nrow];
                    const float xs   = dot * sqrtf(ssqv);
                    const float d2   = ssqv - 2.f * xs + xxv;
                    const float cs   = ((xs - xxv) * (1.f / 63.f)) * rn *
                                       rsqrtf(fmaxf(d2 * (1.f / 3969.f), EPS));
                    sim = wv * cs + bv;
                    pos[R] = sim;
                } else {
                    sim = wv * (dot * rn) + bv;
                }
                s += __expf(sim);
            }
            #pragma unroll
            for (int off = 1; off < 16; off <<= 1) s += __shfl_xor(s, off);
            if (cL == 0)
                Se[waveN * 256 + waveM * 128 + bi * 16 + q * 4 + r] = s;
        }
    }
    __syncthreads();
    if (tid < 256) {
        const float t = Se[tid] + Se[256 + tid] + Se[512 + tid] + Se[768 + tid];
        sumexp2[(size_t)ct * NROWS + rowBase + tid] = t;
    }
}

// K3a: 128 blocks x 256 threads; deterministic tree reduce -> partial[b].
__global__ __launch_bounds__(256) void finalize_part(
    const float* __restrict__ pos, const float* __restrict__ se2,
    float* __restrict__ partial)
{
    const int tid = threadIdx.x;
    const int r   = blockIdx.x * 256 + tid;
    const float s = se2[r] + se2[NROWS + r];
    float acc = __logf(s) - pos[r];
    #pragma unroll
    for (int off = 1; off < 64; off <<= 1) acc += __shfl_xor(acc, off);
    __shared__ float red[4];
    if ((tid & 63) == 0) red[tid >> 6] = acc;
    __syncthreads();
    if (tid == 0) partial[blockIdx.x] = red[0] + red[1] + red[2] + red[3];
}

// K3b: single tiny block sums the 128 partials.
__global__ __launch_bounds__(128) void finalize_sum(
    const float* __restrict__ partial, float* __restrict__ out)
{
    const int tid = threadIdx.x;
    float t = partial[tid];
    #pragma unroll
    for (int off = 1; off < 64; off <<= 1) t += __shfl_xor(t, off);
    __shared__ float red[2];
    if ((tid & 63) == 0) red[tid >> 6] = t;
    __syncthreads();
    if (tid == 0) out[0] = red[0] + red[1];
}

extern "C" void kernel_launch(void* const* d_in, const int* in_sizes, int n_in,
                              void* d_out, int out_size, void* d_ws, size_t ws_size,
                              hipStream_t stream)
{
    const float* x  = (const float*)d_in[0];
    const float* wp = (const float*)d_in[1];
    const float* bp = (const float*)d_in[2];
    float* out = (float*)d_out;

    char* ws = (char*)d_ws;
    size_t off = 0;
    uint16_t* xb      = (uint16_t*)(ws + off); off += (size_t)NROWS * DIM * 2;   // 64 MB
    uint16_t* cmat    = (uint16_t*)(ws + off); off += (size_t)N_SPK * DIM * 2;   // 1 MB
    float*    xxg     = (float*)(ws + off);    off += (size_t)NROWS * 4;
    float*    pos     = (float*)(ws + off);    off += (size_t)NROWS * 4;
    float*    sumexp2 = (float*)(ws + off);    off += (size_t)2 * NROWS * 4;
    float*    ssqg    = (float*)(ws + off);    off += (size_t)N_SPK * 4;
    float*    partial = (float*)(ws + off);    off += (size_t)128 * 4;

    prep_centroid<<<N_SPK, 256, 0, stream>>>(x, xb, cmat, xxg, ssqg);
    gemm_lse_kernel<<<(NROWS / BM2) * (N_SPK / BN2), 512, 0, stream>>>(
        xb, cmat, xxg, ssqg, wp, bp, sumexp2, pos);
    finalize_part<<<NROWS / 256, 256, 0, stream>>>(pos, sumexp2, partial);
    finalize_sum<<<1, 128, 0, stream>>>(partial, out);
}

// Round 5
// 250.794 us; speedup vs baseline: 1.0851x; 1.0106x over previous
//
#include <hip/hip_runtime.h>
#include <stdint.h>

#define N_SPK 512
#define N_UTT 64
#define DIM   1024
#define NROWS (N_SPK * N_UTT)   // 32768
#define EPS   1e-6f

// 256x256 tile, BK=32, 8 waves (2M x 4N), 3-slot LDS ring, counted vmcnt.
#define BM2 256
#define BN2 256
#define BK2 32
#define KT2 (DIM / BK2)         // 32

typedef __attribute__((ext_vector_type(8))) short short8;
typedef __attribute__((ext_vector_type(4))) float f32x4;

__device__ __forceinline__ uint16_t f2bf(float f) {
    union { float f; uint32_t i; } un; un.f = f;
    uint32_t x = un.i;
    return (uint16_t)((x + 0x7fffu + ((x >> 16) & 1u)) >> 16);
}

// K1: one block per speaker (unchanged — measured at BW floor).
__global__ __launch_bounds__(256) void prep_centroid(
    const float* __restrict__ x, uint16_t* __restrict__ xb,
    uint16_t* __restrict__ cmat, float* __restrict__ xxg,
    float* __restrict__ ssqg)
{
    const int n    = blockIdx.x;
    const int tid  = threadIdx.x;
    const int lane = tid & 63;
    const int w    = tid >> 6;

    const float* xn  = x  + (size_t)n * N_UTT * DIM;
    uint16_t*    xbn = xb + (size_t)n * N_UTT * DIM;

    float Sp[16];
    #pragma unroll
    for (int j = 0; j < 16; ++j) Sp[j] = 0.f;

    #pragma unroll 1
    for (int o = 0; o < 4; ++o) {
        const int m0 = w * 16 + o * 4;

        float4 v[16];
        #pragma unroll
        for (int i = 0; i < 4; ++i)
            #pragma unroll
            for (int j = 0; j < 4; ++j)
                v[i * 4 + j] = *(const float4*)(xn + (size_t)(m0 + i) * DIM + j * 256 + lane * 4);

        float xx[4] = {0.f, 0.f, 0.f, 0.f};
        #pragma unroll
        for (int i = 0; i < 4; ++i) {
            #pragma unroll
            for (int j = 0; j < 4; ++j) {
                const float4 qv = v[i * 4 + j];
                xx[i] += qv.x * qv.x + qv.y * qv.y + qv.z * qv.z + qv.w * qv.w;
                Sp[j * 4 + 0] += qv.x; Sp[j * 4 + 1] += qv.y;
                Sp[j * 4 + 2] += qv.z; Sp[j * 4 + 3] += qv.w;
                ushort4 ov;
                ov.x = f2bf(qv.x); ov.y = f2bf(qv.y); ov.z = f2bf(qv.z); ov.w = f2bf(qv.w);
                *(ushort4*)(xbn + (size_t)(m0 + i) * DIM + j * 256 + lane * 4) = ov;
            }
        }

        #pragma unroll
        for (int i = 0; i < 4; ++i) {
            float t = xx[i];
            #pragma unroll
            for (int off = 1; off < 64; off <<= 1) t += __shfl_xor(t, off);
            if (lane == 0) xxg[n * N_UTT + m0 + i] = t;
        }
    }

    __shared__ float Sh[4][DIM];
    #pragma unroll
    for (int j = 0; j < 4; ++j)
        *(float4*)&Sh[w][j * 256 + lane * 4] =
            make_float4(Sp[j * 4], Sp[j * 4 + 1], Sp[j * 4 + 2], Sp[j * 4 + 3]);
    __syncthreads();

    const int d0 = tid * 4;
    float4 S  = *(const float4*)&Sh[0][d0];
    const float4 b1 = *(const float4*)&Sh[1][d0];
    const float4 b2 = *(const float4*)&Sh[2][d0];
    const float4 b3 = *(const float4*)&Sh[3][d0];
    S.x += b1.x + b2.x + b3.x; S.y += b1.y + b2.y + b3.y;
    S.z += b1.z + b2.z + b3.z; S.w += b1.w + b2.w + b3.w;

    float css = S.x * S.x + S.y * S.y + S.z * S.z + S.w * S.w;
    #pragma unroll
    for (int off = 1; off < 64; off <<= 1) css += __shfl_xor(css, off);
    __shared__ float red[4];
    if ((tid & 63) == 0) red[tid >> 6] = css;
    __syncthreads();
    const float ssq = red[0] + red[1] + red[2] + red[3];

    const float scale = rsqrtf(fmaxf(ssq * (1.0f / 4096.f), EPS)) * (1.0f / 64.f);
    ushort4 oc;
    oc.x = f2bf(S.x * scale); oc.y = f2bf(S.y * scale);
    oc.z = f2bf(S.z * scale); oc.w = f2bf(S.w * scale);
    *(ushort4*)(cmat + (size_t)n * DIM + d0) = oc;
    if (tid == 0) ssqg[n] = ssq;
}

// K2: 256x256 bf16 MFMA GEMM, 8 waves, 3-slot LDS ring (96 KB), counted
// vmcnt prefetch depth 2, raw s_barrier, setprio around MFMA.
//
// Per-iter order (race-free): vmcnt(4) [own tile-t loads done] -> s_barrier
// [ALL waves' tile-t loads done + all iter-(t-1) reads done] -> STAGE tile
// t+2 into slot (t+2)%3 == (t-1)%3 [safe: last read iter t-1, barrier-ordered]
// -> ds_read+MFMA tile t. FIFO vmcnt: at iter-t entry outstanding <= 8
// (<=4 of tile t, 4 of tile t+1) so vmcnt(4) proves tile t resident.
// Tail: vmcnt(4) @30 (tiles 30,31 out), vmcnt(0) @31.
// Tiles 3m+c live in slot c (manual 3-step unroll keeps slots literal).
__global__ __launch_bounds__(512, 2) void gemm_lse_kernel(
    const uint16_t* __restrict__ xb, const uint16_t* __restrict__ cmat,
    const float* __restrict__ xxg, const float* __restrict__ ssqg,
    const float* __restrict__ wp, const float* __restrict__ bp,
    float* __restrict__ sumexp2, float* __restrict__ pos)
{
    __shared__ char smem[98304];    // A ring: 3 x 16KB @0; B ring: 3 x 16KB @49152
    float* Se = (float*)smem;       // epilogue alias, [4][256]

    const int tid   = threadIdx.x;
    const int lane  = tid & 63;
    const int wid   = tid >> 6;      // 0..7
    const int waveM = wid >> 2;      // 0..1 (128 rows each)
    const int waveN = wid & 3;       // 0..3 (64 cols each)

    const int bid = blockIdx.x;
    const int rt  = bid & 127;       // A-panel pair (bid, bid+128) -> same XCD
    const int ct  = bid >> 7;

    const int rowBase = rt * BM2;
    const int colBase = ct * BN2;

    // staging: thread handles slots s = i*512+tid (i=0,1); 4 chunks/row @BK=32
    const uint16_t* gAp[2];
    const uint16_t* gBp[2];
    int ldso[2];
    #pragma unroll
    for (int i = 0; i < 2; ++i) {
        const int s    = i * 512 + tid;
        const int srow = s >> 2;                      // 0..255
        const int kc   = (s & 3) ^ ((srow >> 1) & 3); // swizzled chunk fetched
        gAp[i]  = xb   + (size_t)(rowBase + srow) * DIM + kc * 8;
        gBp[i]  = cmat + (size_t)(colBase + srow) * DIM + kc * 8;
        ldso[i] = s * 16;                             // linear LDS byte offset
    }

#define STAGE(slot, kt_)                                                        \
    {                                                                           \
        const int ko_ = (kt_) * BK2;                                            \
        _Pragma("unroll")                                                       \
        for (int i_ = 0; i_ < 2; ++i_) {                                        \
            __builtin_amdgcn_global_load_lds(                                   \
                (const __attribute__((address_space(1))) void*)(gAp[i_] + ko_), \
                (__attribute__((address_space(3))) void*)(smem + (slot) * 16384 + ldso[i_]), \
                16, 0, 0);                                                      \
            __builtin_amdgcn_global_load_lds(                                   \
                (const __attribute__((address_space(1))) void*)(gBp[i_] + ko_), \
                (__attribute__((address_space(3))) void*)(smem + 49152 + (slot) * 16384 + ldso[i_]), \
                16, 0, 0);                                                      \
        }                                                                       \
    }

    f32x4 acc[8][4];
    #pragma unroll
    for (int i = 0; i < 8; ++i)
        #pragma unroll
        for (int j = 0; j < 4; ++j)
            acc[i][j] = (f32x4){0.f, 0.f, 0.f, 0.f};

    const int cL  = lane & 15;
    const int q   = lane >> 4;
    const int kcs = q ^ ((cL >> 1) & 3);   // chunk position to read (all bi/bj)

#define COMPUTE(slot_)                                                          \
    {                                                                           \
        const uint16_t* Ab_ = (const uint16_t*)(smem + (slot_) * 16384);        \
        const uint16_t* Bb_ = (const uint16_t*)(smem + 49152 + (slot_) * 16384);\
        short8 a_[8], b_[4];                                                    \
        _Pragma("unroll")                                                       \
        for (int bi_ = 0; bi_ < 8; ++bi_)                                       \
            a_[bi_] = *(const short8*)&Ab_[(waveM * 128 + bi_ * 16 + cL) * 32 + kcs * 8]; \
        _Pragma("unroll")                                                       \
        for (int bj_ = 0; bj_ < 4; ++bj_)                                       \
            b_[bj_] = *(const short8*)&Bb_[(waveN * 64 + bj_ * 16 + cL) * 32 + kcs * 8]; \
        __builtin_amdgcn_s_setprio(1);                                          \
        _Pragma("unroll")                                                       \
        for (int bi_ = 0; bi_ < 8; ++bi_)                                       \
            _Pragma("unroll")                                                   \
            for (int bj_ = 0; bj_ < 4; ++bj_)                                   \
                acc[bi_][bj_] = __builtin_amdgcn_mfma_f32_16x16x32_bf16(        \
                    a_[bi_], b_[bj_], acc[bi_][bj_], 0, 0, 0);                  \
        __builtin_amdgcn_s_setprio(0);                                          \
    }

// wait own loads (tile t) -> barrier (all waves' tile t resident, all prior
// reads of the stage-target slot done) -> stage tile t+2 -> compute tile t
#define ITER(kt_, cSlot, sSlot)                                                 \
    {                                                                           \
        asm volatile("s_waitcnt vmcnt(4)" ::: "memory");                        \
        __builtin_amdgcn_sched_barrier(0);                                      \
        __builtin_amdgcn_s_barrier();                                           \
        __builtin_amdgcn_sched_barrier(0);                                      \
        STAGE(sSlot, (kt_) + 2);                                                \
        COMPUTE(cSlot);                                                         \
    }

    // prologue: tiles 0,1 in flight (8 loads/thread)
    STAGE(0, 0);
    STAGE(1, 1);

    // t = 0..29: tile 3m+c lives in slot c; stage target slot (c+2)%3
    for (int tb = 0; tb < 30; tb += 3) {
        ITER(tb + 0, 0, 2);
        ITER(tb + 1, 1, 0);
        ITER(tb + 2, 2, 1);
    }
    // t = 30 (slot 0): tiles 30,31 outstanding -> vmcnt(4) proves tile 30
    asm volatile("s_waitcnt vmcnt(4)" ::: "memory");
    __builtin_amdgcn_sched_barrier(0);
    __builtin_amdgcn_s_barrier();
    __builtin_amdgcn_sched_barrier(0);
    COMPUTE(0);
    // t = 31 (slot 1): drain
    asm volatile("s_waitcnt vmcnt(0)" ::: "memory");
    __builtin_amdgcn_sched_barrier(0);
    __builtin_amdgcn_s_barrier();
    __builtin_amdgcn_sched_barrier(0);
    COMPUTE(1);
#undef STAGE
#undef COMPUTE
#undef ITER

    // epilogue: per-row exp-sum into Se[waveN][localRow], diag fixup + pos
    __syncthreads();   // full drain OK here; Se aliases ring slot 0
    const float wv = wp[0], bv = bp[0];
    #pragma unroll
    for (int bi = 0; bi < 8; ++bi) {
        #pragma unroll
        for (int r = 0; r < 4; ++r) {
            const int R     = rowBase + waveM * 128 + bi * 16 + q * 4 + r;
            const float xxv = xxg[R];
            const float rn  = rsqrtf(fmaxf(xxv, EPS));
            const int nrow  = R >> 6;
            float s = 0.f;
            #pragma unroll
            for (int bj = 0; bj < 4; ++bj) {
                const int col = colBase + waveN * 64 + bj * 16 + cL;
                const float dot = acc[bi][bj][r];
                float sim;
                if (col == nrow) {
                    const float ssqv = ssqg[nrow];
                    const float xs   = dot * sqrtf(ssqv);
                    const float d2   = ssqv - 2.f * xs + xxv;
                    const float cs   = ((xs - xxv) * (1.f / 63.f)) * rn *
                                       rsqrtf(fmaxf(d2 * (1.f / 3969.f), EPS));
                    sim = wv * cs + bv;
                    pos[R] = sim;
                } else {
                    sim = wv * (dot * rn) + bv;
                }
                s += __expf(sim);
            }
            #pragma unroll
            for (int off = 1; off < 16; off <<= 1) s += __shfl_xor(s, off);
            if (cL == 0)
                Se[waveN * 256 + waveM * 128 + bi * 16 + q * 4 + r] = s;
        }
    }
    __syncthreads();
    if (tid < 256) {
        const float t = Se[tid] + Se[256 + tid] + Se[512 + tid] + Se[768 + tid];
        sumexp2[(size_t)ct * NROWS + rowBase + tid] = t;
    }
}

// K3a: 128 blocks x 256 threads; deterministic tree reduce -> partial[b].
__global__ __launch_bounds__(256) void finalize_part(
    const float* __restrict__ pos, const float* __restrict__ se2,
    float* __restrict__ partial)
{
    const int tid = threadIdx.x;
    const int r   = blockIdx.x * 256 + tid;
    const float s = se2[r] + se2[NROWS + r];
    float acc = __logf(s) - pos[r];
    #pragma unroll
    for (int off = 1; off < 64; off <<= 1) acc += __shfl_xor(acc, off);
    __shared__ float red[4];
    if ((tid & 63) == 0) red[tid >> 6] = acc;
    __syncthreads();
    if (tid == 0) partial[blockIdx.x] = red[0] + red[1] + red[2] + red[3];
}

// K3b: single tiny block sums the 128 partials.
__global__ __launch_bounds__(128) void finalize_sum(
    const float* __restrict__ partial, float* __restrict__ out)
{
    const int tid = threadIdx.x;
    float t = partial[tid];
    #pragma unroll
    for (int off = 1; off < 64; off <<= 1) t += __shfl_xor(t, off);
    __shared__ float red[2];
    if ((tid & 63) == 0) red[tid >> 6] = t;
    __syncthreads();
    if (tid == 0) out[0] = red[0] + red[1];
}

extern "C" void kernel_launch(void* const* d_in, const int* in_sizes, int n_in,
                              void* d_out, int out_size, void* d_ws, size_t ws_size,
                              hipStream_t stream)
{
    const float* x  = (const float*)d_in[0];
    const float* wp = (const float*)d_in[1];
    const float* bp = (const float*)d_in[2];
    float* out = (float*)d_out;

    char* ws = (char*)d_ws;
    size_t off = 0;
    uint16_t* xb      = (uint16_t*)(ws + off); off += (size_t)NROWS * DIM * 2;   // 64 MB
    uint16_t* cmat    = (uint16_t*)(ws + off); off += (size_t)N_SPK * DIM * 2;   // 1 MB
    float*    xxg     = (float*)(ws + off);    off += (size_t)NROWS * 4;
    float*    pos     = (float*)(ws + off);    off += (size_t)NROWS * 4;
    float*    sumexp2 = (float*)(ws + off);    off += (size_t)2 * NROWS * 4;
    float*    ssqg    = (float*)(ws + off);    off += (size_t)N_SPK * 4;
    float*    partial = (float*)(ws + off);    off += (size_t)128 * 4;

    prep_centroid<<<N_SPK, 256, 0, stream>>>(x, xb, cmat, xxg, ssqg);
    gemm_lse_kernel<<<(NROWS / BM2) * (N_SPK / BN2), 512, 0, stream>>>(
        xb, cmat, xxg, ssqg, wp, bp, sumexp2, pos);
    finalize_part<<<NROWS / 256, 256, 0, stream>>>(pos, sumexp2, partial);
    finalize_sum<<<1, 128, 0, stream>>>(partial, out);
}

// Round 6
// 248.274 us; speedup vs baseline: 1.0961x; 1.0102x over previous
//
#include <hip/hip_runtime.h>
#include <stdint.h>

#define N_SPK 512
#define N_UTT 64
#define DIM   1024
#define NROWS (N_SPK * N_UTT)   // 32768
#define EPS   1e-6f

// GEMM: 256x256 tile, BK=64, 8 waves (2M x 4N), double-buffered (2 K-tiles),
// 4 phases per K-tile, counted-covered vmcnt, conflict-free XOR swizzle.
#define BM2 256
#define BN2 256
#define BK3 64
#define KT3 (DIM / BK3)         // 16

typedef __attribute__((ext_vector_type(8))) short short8;
typedef __attribute__((ext_vector_type(4))) float f32x4;

__device__ __forceinline__ uint16_t f2bf(float f) {
    union { float f; uint32_t i; } un; un.f = f;
    uint32_t x = un.i;
    return (uint16_t)((x + 0x7fffu + ((x >> 16) & 1u)) >> 16);
}

// K1: one block per speaker (unchanged — measured at BW floor).
__global__ __launch_bounds__(256) void prep_centroid(
    const float* __restrict__ x, uint16_t* __restrict__ xb,
    uint16_t* __restrict__ cmat, float* __restrict__ xxg,
    float* __restrict__ ssqg)
{
    const int n    = blockIdx.x;
    const int tid  = threadIdx.x;
    const int lane = tid & 63;
    const int w    = tid >> 6;

    const float* xn  = x  + (size_t)n * N_UTT * DIM;
    uint16_t*    xbn = xb + (size_t)n * N_UTT * DIM;

    float Sp[16];
    #pragma unroll
    for (int j = 0; j < 16; ++j) Sp[j] = 0.f;

    #pragma unroll 1
    for (int o = 0; o < 4; ++o) {
        const int m0 = w * 16 + o * 4;

        float4 v[16];
        #pragma unroll
        for (int i = 0; i < 4; ++i)
            #pragma unroll
            for (int j = 0; j < 4; ++j)
                v[i * 4 + j] = *(const float4*)(xn + (size_t)(m0 + i) * DIM + j * 256 + lane * 4);

        float xx[4] = {0.f, 0.f, 0.f, 0.f};
        #pragma unroll
        for (int i = 0; i < 4; ++i) {
            #pragma unroll
            for (int j = 0; j < 4; ++j) {
                const float4 qv = v[i * 4 + j];
                xx[i] += qv.x * qv.x + qv.y * qv.y + qv.z * qv.z + qv.w * qv.w;
                Sp[j * 4 + 0] += qv.x; Sp[j * 4 + 1] += qv.y;
                Sp[j * 4 + 2] += qv.z; Sp[j * 4 + 3] += qv.w;
                ushort4 ov;
                ov.x = f2bf(qv.x); ov.y = f2bf(qv.y); ov.z = f2bf(qv.z); ov.w = f2bf(qv.w);
                *(ushort4*)(xbn + (size_t)(m0 + i) * DIM + j * 256 + lane * 4) = ov;
            }
        }

        #pragma unroll
        for (int i = 0; i < 4; ++i) {
            float t = xx[i];
            #pragma unroll
            for (int off = 1; off < 64; off <<= 1) t += __shfl_xor(t, off);
            if (lane == 0) xxg[n * N_UTT + m0 + i] = t;
        }
    }

    __shared__ float Sh[4][DIM];
    #pragma unroll
    for (int j = 0; j < 4; ++j)
        *(float4*)&Sh[w][j * 256 + lane * 4] =
            make_float4(Sp[j * 4], Sp[j * 4 + 1], Sp[j * 4 + 2], Sp[j * 4 + 3]);
    __syncthreads();

    const int d0 = tid * 4;
    float4 S  = *(const float4*)&Sh[0][d0];
    const float4 b1 = *(const float4*)&Sh[1][d0];
    const float4 b2 = *(const float4*)&Sh[2][d0];
    const float4 b3 = *(const float4*)&Sh[3][d0];
    S.x += b1.x + b2.x + b3.x; S.y += b1.y + b2.y + b3.y;
    S.z += b1.z + b2.z + b3.z; S.w += b1.w + b2.w + b3.w;

    float css = S.x * S.x + S.y * S.y + S.z * S.z + S.w * S.w;
    #pragma unroll
    for (int off = 1; off < 64; off <<= 1) css += __shfl_xor(css, off);
    __shared__ float red[4];
    if ((tid & 63) == 0) red[tid >> 6] = css;
    __syncthreads();
    const float ssq = red[0] + red[1] + red[2] + red[3];

    const float scale = rsqrtf(fmaxf(ssq * (1.0f / 4096.f), EPS)) * (1.0f / 64.f);
    ushort4 oc;
    oc.x = f2bf(S.x * scale); oc.y = f2bf(S.y * scale);
    oc.z = f2bf(S.z * scale); oc.w = f2bf(S.w * scale);
    *(ushort4*)(cmat + (size_t)n * DIM + d0) = oc;
    if (tid == 0) ssqg[n] = ssq;
}

// K2: 256x256 bf16 MFMA GEMM, BK=64, 8 waves, dbuf LDS (128 KB), 4 phases
// per K-tile with interleaved half-tile staging, setprio around MFMA.
//
// LDS: A[buf][half]: smem + buf*32768 + half*16384 (half = 128 rows x 64 K)
//      B[buf][half]: smem + 65536 + buf*32768 + half*16384
// Swizzle: row's 8 chunks (8 bf16 = 16B each) stored at p = c ^ (row&7);
// read logical chunk c = ks*4+q at p — fully conflict-free ds_read_b128
// (8 lanes/bank-quad = b128 minimum).
//
// Per K-tile kt (buf = kt&1), hazards:
//  * entry: vmcnt(0) waits exactly kt's 8 loads (all older retired FIFO at
//    kt-1 entry; kt+1's not yet issued) — covered by >=2 phases of issue
//    distance; s_barrier then certifies kt resident for ALL waves and that
//    all waves finished kt-1's reads (their last reg-load was lgkm-waited
//    before kt-1's final MFMA, ordered by phase barriers).
//  * phases read buf only, stage into buf^1 only (kt+1) — no intra-tile
//    hazard; all intra-tile barriers are scheduling-only.
__global__ __launch_bounds__(512, 2) void gemm_lse_kernel(
    const uint16_t* __restrict__ xb, const uint16_t* __restrict__ cmat,
    const float* __restrict__ xxg, const float* __restrict__ ssqg,
    const float* __restrict__ wp, const float* __restrict__ bp,
    float* __restrict__ sumexp2, float* __restrict__ pos)
{
    __shared__ char smem[131072];
    float* Se = (float*)smem;        // epilogue alias

    const int tid   = threadIdx.x;
    const int lane  = tid & 63;
    const int wid   = tid >> 6;      // 0..7
    const int waveM = wid >> 2;      // 0..1 (128 rows each)
    const int waveN = wid & 3;       // 0..3 (64 cols each)

    const int bid = blockIdx.x;
    const int rt  = bid & 127;       // A-panel pair (bid, bid+128) -> same XCD
    const int ct  = bid >> 7;

    const int rowBase = rt * BM2;
    const int colBase = ct * BN2;

    // staging precompute: slots s = tid, tid+512 within each 16KB half-tile
    int aoff[2];    // element offset within a half-panel: row*1024 + c*8
    int ldsb[2];    // linear LDS byte offset within a half buffer
    #pragma unroll
    for (int i = 0; i < 2; ++i) {
        const int s   = tid + i * 512;
        const int row = s >> 3;                  // 0..127
        const int c   = (s & 7) ^ (row & 7);     // logical chunk fetched
        aoff[i] = row * 1024 + c * 8;
        ldsb[i] = s * 16;
    }
    const uint16_t* Abase = xb   + (size_t)rowBase * DIM;
    const uint16_t* Bbase = cmat + (size_t)colBase * DIM;

// stage one 128-row half-panel (2 x 16B loads/thread)
#define STAGEH(matBase, ldsMatOff, buf, h, kt_)                                 \
    { _Pragma("unroll")                                                         \
      for (int i_ = 0; i_ < 2; ++i_) {                                          \
        __builtin_amdgcn_global_load_lds(                                       \
            (const __attribute__((address_space(1))) void*)(                    \
                (matBase) + (size_t)(h) * 131072 + (kt_) * 64 + aoff[i_]),      \
            (__attribute__((address_space(3))) void*)(                          \
                smem + (ldsMatOff) + (buf) * 32768 + (h) * 16384 + ldsb[i_]),   \
            16, 0, 0); } }

    f32x4 acc[8][4];
    #pragma unroll
    for (int i = 0; i < 8; ++i)
        #pragma unroll
        for (int j = 0; j < 4; ++j)
            acc[i][j] = (f32x4){0.f, 0.f, 0.f, 0.f};

    const int cL  = lane & 15;
    const int q   = lane >> 4;
    const int pk0 = ((q ^ (cL & 7)) * 16);   // stored-chunk byte off, ks=0
    // ks=1: logical chunk 4+q = (q)^4 -> stored byte = pk0 ^ 64

#define READ_A(buf, bi0, pk, dest)                                              \
    { const char* Ab_ = smem + (buf) * 32768 + waveM * 16384;                   \
      _Pragma("unroll")                                                         \
      for (int i_ = 0; i_ < 4; ++i_)                                            \
        dest[i_] = *(const short8*)(Ab_ + ((bi0) + i_) * 2048 + cL * 128 + (pk)); }

#define READ_B(buf, pk, dest)                                                   \
    { const char* Bb_ = smem + 65536 + (buf) * 32768 + (waveN >> 1) * 16384;    \
      _Pragma("unroll")                                                         \
      for (int j_ = 0; j_ < 4; ++j_)                                            \
        dest[j_] = *(const short8*)(Bb_ + ((waveN & 1) * 64 + j_ * 16 + cL) * 128 + (pk)); }

#define MFMA16(bi0, av, bv)                                                     \
    { __builtin_amdgcn_s_setprio(1);                                            \
      _Pragma("unroll")                                                         \
      for (int i_ = 0; i_ < 4; ++i_)                                            \
        _Pragma("unroll")                                                       \
        for (int j_ = 0; j_ < 4; ++j_)                                          \
          acc[(bi0) + i_][j_] = __builtin_amdgcn_mfma_f32_16x16x32_bf16(        \
              av[i_], bv[j_], acc[(bi0) + i_][j_], 0, 0, 0);                    \
      __builtin_amdgcn_s_setprio(0); }

#define SBAR()  { __builtin_amdgcn_sched_barrier(0);                            \
                  __builtin_amdgcn_s_barrier();                                 \
                  __builtin_amdgcn_sched_barrier(0); }

#define KTILE(buf, kt_, DO_STAGE)                                               \
    {                                                                           \
        asm volatile("s_waitcnt vmcnt(0)" ::: "memory");                        \
        SBAR();                                                                 \
        short8 a0[4], a1[4], b0[4], b1[4];                                      \
        /* phase 0: Q(bi0-3,ks0); stage A halves of kt+1 */                     \
        READ_A(buf, 0, pk0, a0); READ_B(buf, pk0, b0);                          \
        if (DO_STAGE) { STAGEH(Abase, 0, (buf) ^ 1, 0, (kt_) + 1);              \
                        STAGEH(Abase, 0, (buf) ^ 1, 1, (kt_) + 1); }            \
        SBAR();                                                                 \
        MFMA16(0, a0, b0);                                                      \
        SBAR();                                                                 \
        /* phase 1: Q(bi4-7,ks0); stage B halves of kt+1 */                     \
        READ_A(buf, 4, pk0, a1);                                                \
        if (DO_STAGE) { STAGEH(Bbase, 65536, (buf) ^ 1, 0, (kt_) + 1);          \
                        STAGEH(Bbase, 65536, (buf) ^ 1, 1, (kt_) + 1); }        \
        SBAR();                                                                 \
        MFMA16(4, a1, b0);                                                      \
        SBAR();                                                                 \
        /* phase 2: Q(bi0-3,ks1) */                                             \
        READ_A(buf, 0, pk0 ^ 64, a0); READ_B(buf, pk0 ^ 64, b1);                \
        SBAR();                                                                 \
        MFMA16(0, a0, b1);                                                      \
        SBAR();                                                                 \
        /* phase 3: Q(bi4-7,ks1) */                                             \
        READ_A(buf, 4, pk0 ^ 64, a1);                                           \
        SBAR();                                                                 \
        MFMA16(4, a1, b1);                                                      \
        /* tile-end sync merges into next tile's entry */                       \
    }

    // prologue: K-tile 0 into buf 0 (8 loads/thread)
    STAGEH(Abase, 0, 0, 0, 0); STAGEH(Abase, 0, 0, 1, 0);
    STAGEH(Bbase, 65536, 0, 0, 0); STAGEH(Bbase, 65536, 0, 1, 0);

    #pragma unroll 1
    for (int ktp = 0; ktp < KT3 - 2; ktp += 2) {   // kt = 0..13
        KTILE(0, ktp, 1);
        KTILE(1, ktp + 1, 1);
    }
    KTILE(0, KT3 - 2, 1);     // kt=14, stages kt=15
    KTILE(1, KT3 - 1, 0);     // kt=15, no stage
#undef STAGEH
#undef READ_A
#undef READ_B
#undef MFMA16
#undef SBAR
#undef KTILE

    // epilogue: per-row exp-sum into Se[waveN][localRow], diag fixup + pos
    __syncthreads();
    const float wv = wp[0], bv = bp[0];
    #pragma unroll
    for (int bi = 0; bi < 8; ++bi) {
        #pragma unroll
        for (int r = 0; r < 4; ++r) {
            const int R     = rowBase + waveM * 128 + bi * 16 + q * 4 + r;
            const float xxv = xxg[R];
            const float rn  = rsqrtf(fmaxf(xxv, EPS));
            const int nrow  = R >> 6;
            float s = 0.f;
            #pragma unroll
            for (int bj = 0; bj < 4; ++bj) {
                const int col = colBase + waveN * 64 + bj * 16 + cL;
                const float dot = acc[bi][bj][r];
                float sim;
                if (col == nrow) {
                    const float ssqv = ssqg[nrow];
                    const float xs   = dot * sqrtf(ssqv);
                    const float d2   = ssqv - 2.f * xs + xxv;
                    const float cs   = ((xs - xxv) * (1.f / 63.f)) * rn *
                                       rsqrtf(fmaxf(d2 * (1.f / 3969.f), EPS));
                    sim = wv * cs + bv;
                    pos[R] = sim;
                } else {
                    sim = wv * (dot * rn) + bv;
                }
                s += __expf(sim);
            }
            #pragma unroll
            for (int off = 1; off < 16; off <<= 1) s += __shfl_xor(s, off);
            if (cL == 0)
                Se[waveN * 256 + waveM * 128 + bi * 16 + q * 4 + r] = s;
        }
    }
    __syncthreads();
    if (tid < 256) {
        const float t = Se[tid] + Se[256 + tid] + Se[512 + tid] + Se[768 + tid];
        sumexp2[(size_t)ct * NROWS + rowBase + tid] = t;
    }
}

// K3a: 128 blocks x 256 threads; deterministic tree reduce -> partial[b].
__global__ __launch_bounds__(256) void finalize_part(
    const float* __restrict__ pos, const float* __restrict__ se2,
    float* __restrict__ partial)
{
    const int tid = threadIdx.x;
    const int r   = blockIdx.x * 256 + tid;
    const float s = se2[r] + se2[NROWS + r];
    float acc = __logf(s) - pos[r];
    #pragma unroll
    for (int off = 1; off < 64; off <<= 1) acc += __shfl_xor(acc, off);
    __shared__ float red[4];
    if ((tid & 63) == 0) red[tid >> 6] = acc;
    __syncthreads();
    if (tid == 0) partial[blockIdx.x] = red[0] + red[1] + red[2] + red[3];
}

// K3b: single tiny block sums the 128 partials.
__global__ __launch_bounds__(128) void finalize_sum(
    const float* __restrict__ partial, float* __restrict__ out)
{
    const int tid = threadIdx.x;
    float t = partial[tid];
    #pragma unroll
    for (int off = 1; off < 64; off <<= 1) t += __shfl_xor(t, off);
    __shared__ float red[2];
    if ((tid & 63) == 0) red[tid >> 6] = t;
    __syncthreads();
    if (tid == 0) out[0] = red[0] + red[1];
}

extern "C" void kernel_launch(void* const* d_in, const int* in_sizes, int n_in,
                              void* d_out, int out_size, void* d_ws, size_t ws_size,
                              hipStream_t stream)
{
    const float* x  = (const float*)d_in[0];
    const float* wp = (const float*)d_in[1];
    const float* bp = (const float*)d_in[2];
    float* out = (float*)d_out;

    char* ws = (char*)d_ws;
    size_t off = 0;
    uint16_t* xb      = (uint16_t*)(ws + off); off += (size_t)NROWS * DIM * 2;   // 64 MB
    uint16_t* cmat    = (uint16_t*)(ws + off); off += (size_t)N_SPK * DIM * 2;   // 1 MB
    float*    xxg     = (float*)(ws + off);    off += (size_t)NROWS * 4;
    float*    pos     = (float*)(ws + off);    off += (size_t)NROWS * 4;
    float*    sumexp2 = (float*)(ws + off);    off += (size_t)2 * NROWS * 4;
    float*    ssqg    = (float*)(ws + off);    off += (size_t)N_SPK * 4;
    float*    partial = (float*)(ws + off);    off += (size_t)128 * 4;

    prep_centroid<<<N_SPK, 256, 0, stream>>>(x, xb, cmat, xxg, ssqg);
    gemm_lse_kernel<<<(NROWS / BM2) * (N_SPK / BN2), 512, 0, stream>>>(
        xb, cmat, xxg, ssqg, wp, bp, sumexp2, pos);
    finalize_part<<<NROWS / 256, 256, 0, stream>>>(pos, sumexp2, partial);
    finalize_sum<<<1, 128, 0, stream>>>(partial, out);
}

// Round 7
// 243.904 us; speedup vs baseline: 1.1158x; 1.0179x over previous
//
#include <hip/hip_runtime.h>
#include <stdint.h>

#define N_SPK 512
#define N_UTT 64
#define DIM   1024
#define NROWS (N_SPK * N_UTT)   // 32768
#define EPS   1e-6f

// GEMM: 128 rows x 512 cols (FULL speaker axis) per block, BK=32,
// 8 waves (2M x 4N), wave-tile 64x128, 3-slot LDS ring, counted vmcnt.
#define BMF 128
#define BNF 512
#define BKF 32
#define KTF (DIM / BKF)         // 32
#define SLOT_BYTES 40960        // A 8KB + B 32KB

typedef __attribute__((ext_vector_type(8))) short short8;
typedef __attribute__((ext_vector_type(4))) float f32x4;

__device__ __forceinline__ uint16_t f2bf(float f) {
    union { float f; uint32_t i; } un; un.f = f;
    uint32_t x = un.i;
    return (uint16_t)((x + 0x7fffu + ((x >> 16) & 1u)) >> 16);
}

// K1: one block per speaker (unchanged — measured at BW floor).
__global__ __launch_bounds__(256) void prep_centroid(
    const float* __restrict__ x, uint16_t* __restrict__ xb,
    uint16_t* __restrict__ cmat, float* __restrict__ xxg,
    float* __restrict__ ssqg)
{
    const int n    = blockIdx.x;
    const int tid  = threadIdx.x;
    const int lane = tid & 63;
    const int w    = tid >> 6;

    const float* xn  = x  + (size_t)n * N_UTT * DIM;
    uint16_t*    xbn = xb + (size_t)n * N_UTT * DIM;

    float Sp[16];
    #pragma unroll
    for (int j = 0; j < 16; ++j) Sp[j] = 0.f;

    #pragma unroll 1
    for (int o = 0; o < 4; ++o) {
        const int m0 = w * 16 + o * 4;

        float4 v[16];
        #pragma unroll
        for (int i = 0; i < 4; ++i)
            #pragma unroll
            for (int j = 0; j < 4; ++j)
                v[i * 4 + j] = *(const float4*)(xn + (size_t)(m0 + i) * DIM + j * 256 + lane * 4);

        float xx[4] = {0.f, 0.f, 0.f, 0.f};
        #pragma unroll
        for (int i = 0; i < 4; ++i) {
            #pragma unroll
            for (int j = 0; j < 4; ++j) {
                const float4 qv = v[i * 4 + j];
                xx[i] += qv.x * qv.x + qv.y * qv.y + qv.z * qv.z + qv.w * qv.w;
                Sp[j * 4 + 0] += qv.x; Sp[j * 4 + 1] += qv.y;
                Sp[j * 4 + 2] += qv.z; Sp[j * 4 + 3] += qv.w;
                ushort4 ov;
                ov.x = f2bf(qv.x); ov.y = f2bf(qv.y); ov.z = f2bf(qv.z); ov.w = f2bf(qv.w);
                *(ushort4*)(xbn + (size_t)(m0 + i) * DIM + j * 256 + lane * 4) = ov;
            }
        }

        #pragma unroll
        for (int i = 0; i < 4; ++i) {
            float t = xx[i];
            #pragma unroll
            for (int off = 1; off < 64; off <<= 1) t += __shfl_xor(t, off);
            if (lane == 0) xxg[n * N_UTT + m0 + i] = t;
        }
    }

    __shared__ float Sh[4][DIM];
    #pragma unroll
    for (int j = 0; j < 4; ++j)
        *(float4*)&Sh[w][j * 256 + lane * 4] =
            make_float4(Sp[j * 4], Sp[j * 4 + 1], Sp[j * 4 + 2], Sp[j * 4 + 3]);
    __syncthreads();

    const int d0 = tid * 4;
    float4 S  = *(const float4*)&Sh[0][d0];
    const float4 b1 = *(const float4*)&Sh[1][d0];
    const float4 b2 = *(const float4*)&Sh[2][d0];
    const float4 b3 = *(const float4*)&Sh[3][d0];
    S.x += b1.x + b2.x + b3.x; S.y += b1.y + b2.y + b3.y;
    S.z += b1.z + b2.z + b3.z; S.w += b1.w + b2.w + b3.w;

    float css = S.x * S.x + S.y * S.y + S.z * S.z + S.w * S.w;
    #pragma unroll
    for (int off = 1; off < 64; off <<= 1) css += __shfl_xor(css, off);
    __shared__ float red[4];
    if ((tid & 63) == 0) red[tid >> 6] = css;
    __syncthreads();
    const float ssq = red[0] + red[1] + red[2] + red[3];

    const float scale = rsqrtf(fmaxf(ssq * (1.0f / 4096.f), EPS)) * (1.0f / 64.f);
    ushort4 oc;
    oc.x = f2bf(S.x * scale); oc.y = f2bf(S.y * scale);
    oc.z = f2bf(S.z * scale); oc.w = f2bf(S.w * scale);
    *(ushort4*)(cmat + (size_t)n * DIM + d0) = oc;
    if (tid == 0) ssqg[n] = ssq;
}

// K2: full-row GEMM+LSE. Each block: 128 rows x ALL 512 cols, so the row
// exp-sum AND the diagonal term complete in-block -> one float out per block.
// Deletes finalize_part, pos[], sumexp2[]; each xb row fetched exactly once;
// cmat (1MB) L2-resident per XCD.
// Schedule = r5's proven ring: per iter t: vmcnt(5) [own tile-t loads done,
// FIFO: 5 newer loads = tile t+1] -> s_barrier [all waves' tile-t resident +
// all iter-(t-1) reads done] -> STAGE tile t+2 into slot (t+2)%3 == (t-1)%3
// -> ds_read+MFMA tile t. Tail: vmcnt(5) @30, vmcnt(0) @31.
// Swizzle (r2-proven): stage kc=(s&3)^((row>>1)&3); read kcs=q^((cL>>1)&3)
// -> 2-way bank aliasing on ds_read_b128 (free, m136).
__global__ __launch_bounds__(512, 1) void gemm_lse_kernel(
    const uint16_t* __restrict__ xb, const uint16_t* __restrict__ cmat,
    const float* __restrict__ xxg, const float* __restrict__ ssqg,
    const float* __restrict__ wp, const float* __restrict__ bp,
    float* __restrict__ partial)
{
    __shared__ char smem[3 * SLOT_BYTES];   // 120 KB ring; epilogue aliases base

    const int tid   = threadIdx.x;
    const int lane  = tid & 63;
    const int wid   = tid >> 6;      // 0..7
    const int waveM = wid >> 2;      // 0..1 (64 rows each)
    const int waveN = wid & 3;       // 0..3 (128 cols each)

    const int rowBase = blockIdx.x * BMF;

    // staging: 5 x 16B loads/thread/K-tile. i=0 covers A (512 slots);
    // i=1..4 cover B (2048 slots). ldso = wave-base + lane*16 pattern
    // (matches global_load_lds lane-linear dest, proven r2..r6).
    const uint16_t* gsrc[5];
    int ldso[5];
    {
        const int srow = tid >> 2;
        const int kc   = (tid & 3) ^ ((srow >> 1) & 3);
        gsrc[0] = xb + (size_t)(rowBase + srow) * DIM + kc * 8;
        ldso[0] = tid * 16;
    }
    #pragma unroll
    for (int i = 1; i < 5; ++i) {
        const int s    = tid + (i - 1) * 512;     // 0..2047
        const int brow = s >> 2;                  // 0..511
        const int kc   = (s & 3) ^ ((brow >> 1) & 3);
        gsrc[i] = cmat + (size_t)brow * DIM + kc * 8;
        ldso[i] = 8192 + s * 16;
    }

#define STAGE(slot, kt_)                                                        \
    { _Pragma("unroll")                                                         \
      for (int i_ = 0; i_ < 5; ++i_) {                                          \
        __builtin_amdgcn_global_load_lds(                                       \
            (const __attribute__((address_space(1))) void*)(gsrc[i_] + (kt_) * BKF), \
            (__attribute__((address_space(3))) void*)(smem + (slot) * SLOT_BYTES + ldso[i_]), \
            16, 0, 0); } }

    f32x4 acc[4][8];
    #pragma unroll
    for (int i = 0; i < 4; ++i)
        #pragma unroll
        for (int j = 0; j < 8; ++j)
            acc[i][j] = (f32x4){0.f, 0.f, 0.f, 0.f};

    const int cL  = lane & 15;
    const int q   = lane >> 4;
    const int kcs = q ^ ((cL >> 1) & 3);

#define COMPUTE(slot_)                                                          \
    {                                                                           \
        const char* Ab_ = smem + (slot_) * SLOT_BYTES;                          \
        const char* Bb_ = smem + (slot_) * SLOT_BYTES + 8192;                   \
        short8 a_[4], b_[8];                                                    \
        _Pragma("unroll")                                                       \
        for (int bi_ = 0; bi_ < 4; ++bi_)                                       \
            a_[bi_] = *(const short8*)(Ab_ + (waveM * 64 + bi_ * 16 + cL) * 64 + kcs * 16); \
        _Pragma("unroll")                                                       \
        for (int bj_ = 0; bj_ < 8; ++bj_)                                       \
            b_[bj_] = *(const short8*)(Bb_ + (waveN * 128 + bj_ * 16 + cL) * 64 + kcs * 16); \
        __builtin_amdgcn_s_setprio(1);                                          \
        _Pragma("unroll")                                                       \
        for (int bi_ = 0; bi_ < 4; ++bi_)                                       \
            _Pragma("unroll")                                                   \
            for (int bj_ = 0; bj_ < 8; ++bj_)                                   \
                acc[bi_][bj_] = __builtin_amdgcn_mfma_f32_16x16x32_bf16(        \
                    a_[bi_], b_[bj_], acc[bi_][bj_], 0, 0, 0);                  \
        __builtin_amdgcn_s_setprio(0);                                          \
    }

#define ITER(kt_, cSlot, sSlot)                                                 \
    {                                                                           \
        asm volatile("s_waitcnt vmcnt(5)" ::: "memory");                        \
        __builtin_amdgcn_sched_barrier(0);                                      \
        __builtin_amdgcn_s_barrier();                                           \
        __builtin_amdgcn_sched_barrier(0);                                      \
        STAGE(sSlot, (kt_) + 2);                                                \
        COMPUTE(cSlot);                                                         \
    }

    // prologue: tiles 0,1 in flight (10 loads/thread)
    STAGE(0, 0);
    STAGE(1, 1);

    for (int tb = 0; tb < 30; tb += 3) {   // t = 0..29
        ITER(tb + 0, 0, 2);
        ITER(tb + 1, 1, 0);
        ITER(tb + 2, 2, 1);
    }
    // t = 30 (slot 0): tile 31's 5 loads outstanding -> vmcnt(5)
    asm volatile("s_waitcnt vmcnt(5)" ::: "memory");
    __builtin_amdgcn_sched_barrier(0);
    __builtin_amdgcn_s_barrier();
    __builtin_amdgcn_sched_barrier(0);
    COMPUTE(0);
    // t = 31 (slot 1): drain
    asm volatile("s_waitcnt vmcnt(0)" ::: "memory");
    __builtin_amdgcn_sched_barrier(0);
    __builtin_amdgcn_s_barrier();
    __builtin_amdgcn_sched_barrier(0);
    COMPUTE(1);
#undef STAGE
#undef COMPUTE
#undef ITER

    // epilogue: full-row LSE in-block. Se[4][128] exp-sums, Pe[128] diag sims.
    __syncthreads();
    float* Se  = (float*)smem;                 // 2048 B
    float* Pe  = (float*)(smem + 2048);        // 512 B
    float* red = (float*)(smem + 2560);        // 8 B

    const float wv = wp[0], bv = bp[0];
    #pragma unroll
    for (int bi = 0; bi < 4; ++bi) {
        #pragma unroll
        for (int r = 0; r < 4; ++r) {
            const int lr    = waveM * 64 + bi * 16 + q * 4 + r;   // 0..127
            const int R     = rowBase + lr;
            const float xxv = xxg[R];
            const float rn  = rsqrtf(fmaxf(xxv, EPS));
            const int nrow  = R >> 6;                              // 0..511
            float s = 0.f;
            #pragma unroll
            for (int bj = 0; bj < 8; ++bj) {
                const int col = waveN * 128 + bj * 16 + cL;
                const float dot = acc[bi][bj][r];
                float sim;
                if (col == nrow) {
                    const float ssqv = ssqg[nrow];
                    const float xs   = dot * sqrtf(ssqv);
                    const float d2   = ssqv - 2.f * xs + xxv;
                    const float cs   = ((xs - xxv) * (1.f / 63.f)) * rn *
                                       rsqrtf(fmaxf(d2 * (1.f / 3969.f), EPS));
                    sim = wv * cs + bv;
                    Pe[lr] = sim;              // exactly one lane per row
                } else {
                    sim = wv * (dot * rn) + bv;
                }
                s += __expf(sim);
            }
            #pragma unroll
            for (int off = 1; off < 16; off <<= 1) s += __shfl_xor(s, off);
            if (cL == 0) Se[waveN * 128 + lr] = s;
        }
    }
    __syncthreads();
    if (tid < 128) {
        const float tot = Se[tid] + Se[128 + tid] + Se[256 + tid] + Se[384 + tid];
        float lt = __logf(tot) - Pe[tid];
        #pragma unroll
        for (int off = 1; off < 64; off <<= 1) lt += __shfl_xor(lt, off);
        if ((tid & 63) == 0) red[tid >> 6] = lt;
    }
    __syncthreads();
    if (tid == 0) partial[blockIdx.x] = red[0] + red[1];
}

// K3: single block sums the 256 per-block partials (deterministic tree).
__global__ __launch_bounds__(256) void finalize_sum(
    const float* __restrict__ partial, float* __restrict__ out)
{
    const int tid = threadIdx.x;
    float t = partial[tid];
    #pragma unroll
    for (int off = 1; off < 64; off <<= 1) t += __shfl_xor(t, off);
    __shared__ float red[4];
    if ((tid & 63) == 0) red[tid >> 6] = t;
    __syncthreads();
    if (tid == 0) out[0] = red[0] + red[1] + red[2] + red[3];
}

extern "C" void kernel_launch(void* const* d_in, const int* in_sizes, int n_in,
                              void* d_out, int out_size, void* d_ws, size_t ws_size,
                              hipStream_t stream)
{
    const float* x  = (const float*)d_in[0];
    const float* wp = (const float*)d_in[1];
    const float* bp = (const float*)d_in[2];
    float* out = (float*)d_out;

    char* ws = (char*)d_ws;
    size_t off = 0;
    uint16_t* xb      = (uint16_t*)(ws + off); off += (size_t)NROWS * DIM * 2;   // 64 MB
    uint16_t* cmat    = (uint16_t*)(ws + off); off += (size_t)N_SPK * DIM * 2;   // 1 MB
    float*    xxg     = (float*)(ws + off);    off += (size_t)NROWS * 4;
    float*    ssqg    = (float*)(ws + off);    off += (size_t)N_SPK * 4;
    float*    partial = (float*)(ws + off);    off += (size_t)256 * 4;

    prep_centroid<<<N_SPK, 256, 0, stream>>>(x, xb, cmat, xxg, ssqg);
    gemm_lse_kernel<<<NROWS / BMF, 512, 0, stream>>>(
        xb, cmat, xxg, ssqg, wp, bp, partial);
    finalize_sum<<<1, 256, 0, stream>>>(partial, out);
}